// Round 1
// baseline (1328.714 us; speedup 1.0000x reference)
//
#include <hip/hip_runtime.h>

// Rotation_agg: metapath_features (N,4,64) fp32, r_vec (4,32,2) fp32.
// out[n, 2c:2c+2] = 0.25 * ( a0*F0[c] + a1*F1[c] + a2*F2[c] + a3 )   (complex mul)
// where F2 = conj(rv2), F1 = F2*conj(rv1), F0 = F1*rv0, rv_e = normalize(r_vec[e]).
// (ETYPES=[0,3,5] -> rv_full[0]=rv0, rv_full[3]=conj(rv1), rv_full[5]=conj(rv2))
// Memory-bound: 1.28 GB/launch -> ~203 us floor at 6.3 TB/s.

__global__ __launch_bounds__(256) void rot_agg_kernel(
    const float4* __restrict__ feat,   // N*64 float4  (= N,4,64 floats)
    const float*  __restrict__ r_vec,  // 4*32*2 floats
    float4*       __restrict__ out,    // N*16 float4  (= N,64 floats)
    long long total)                   // N*16 threads
{
    long long t = (long long)blockIdx.x * 256 + threadIdx.x;
    if (t >= total) return;
    int q = (int)(t & 15);        // float4 index within node = complex pair (2q, 2q+1)
    long long n = t >> 4;

    // --- per-complex-index rotation coefficients for c = 2q and 2q+1 ---
    float F0r[2], F0i[2], F1r[2], F1i[2], F2r[2], F2i[2];
#pragma unroll
    for (int k = 0; k < 2; ++k) {
        int c = 2 * q + k;
        float rvr[3], rvi[3];
#pragma unroll
        for (int e = 0; e < 3; ++e) {
            float re = r_vec[(e * 32 + c) * 2];
            float im = r_vec[(e * 32 + c) * 2 + 1];
            float inv = 1.0f / fmaxf(sqrtf(re * re + im * im), 1e-12f);
            rvr[e] = re * inv;
            rvi[e] = im * inv;
        }
        // F2 = conj(rv2)
        F2r[k] = rvr[2];
        F2i[k] = -rvi[2];
        // F1 = F2 * conj(rv1):  (x+iy)(a-ib) = (xa+yb) + i(ya-xb)
        F1r[k] = F2r[k] * rvr[1] + F2i[k] * rvi[1];
        F1i[k] = F2i[k] * rvr[1] - F2r[k] * rvi[1];
        // F0 = F1 * rv0:  (x+iy)(a+ib) = (xa-yb) + i(xb+ya)
        F0r[k] = F1r[k] * rvr[0] - F1i[k] * rvi[0];
        F0i[k] = F1r[k] * rvi[0] + F1i[k] * rvr[0];
    }

    // --- load 4 layers (each node row = 256 floats = 64 float4, layer stride 16 float4) ---
    const float4* fp = feat + n * 64;
    float4 a0 = fp[q];
    float4 a1 = fp[16 + q];
    float4 a2 = fp[32 + q];
    float4 a3 = fp[48 + q];

    // --- rotate + accumulate + mean ---
    // complex slot 0: (a.x, a.y); slot 1: (a.z, a.w)
    float r0 = a0.x * F0r[0] - a0.y * F0i[0]
             + a1.x * F1r[0] - a1.y * F1i[0]
             + a2.x * F2r[0] - a2.y * F2i[0]
             + a3.x;
    float i0 = a0.x * F0i[0] + a0.y * F0r[0]
             + a1.x * F1i[0] + a1.y * F1r[0]
             + a2.x * F2i[0] + a2.y * F2r[0]
             + a3.y;
    float r1 = a0.z * F0r[1] - a0.w * F0i[1]
             + a1.z * F1r[1] - a1.w * F1i[1]
             + a2.z * F2r[1] - a2.w * F2i[1]
             + a3.z;
    float i1 = a0.z * F0i[1] + a0.w * F0r[1]
             + a1.z * F1i[1] + a1.w * F1r[1]
             + a2.z * F2i[1] + a2.w * F2r[1]
             + a3.w;

    out[n * 16 + q] = make_float4(r0 * 0.25f, i0 * 0.25f, r1 * 0.25f, i1 * 0.25f);
}

extern "C" void kernel_launch(void* const* d_in, const int* in_sizes, int n_in,
                              void* d_out, int out_size, void* d_ws, size_t ws_size,
                              hipStream_t stream) {
    const float* feat  = (const float*)d_in[0];   // (N,4,64)
    const float* r_vec = (const float*)d_in[1];   // (4,32,2)
    float* out = (float*)d_out;                   // (N,64)

    long long N = (long long)in_sizes[0] / 256;   // 4*64 floats per node
    long long total = N * 16;                     // one thread per output float4
    int block = 256;
    long long grid = (total + block - 1) / block;

    rot_agg_kernel<<<(unsigned)grid, block, 0, stream>>>(
        (const float4*)feat, r_vec, (float4*)out, total);
}